// Round 5
// baseline (497.636 us; speedup 1.0000x reference)
//
#include <hip/hip_runtime.h>
#include <hip/hip_cooperative_groups.h>
#include <math.h>

#define Bq 8
#define Tq 4096
#define Dq 512
#define Hq 512
#define Mq (Bq * Tq)   // 32768
#define NC 64          // chunks along T
#define CL 64          // chunk length

typedef unsigned short ushort_t;
typedef unsigned int uint_t;
typedef __bf16 bf16x8 __attribute__((ext_vector_type(8)));
typedef float f32x4 __attribute__((ext_vector_type(4)));

__device__ __forceinline__ ushort_t f2bf(float f) {
    unsigned int u = __float_as_uint(f);
    unsigned int r = u + 0x7fffu + ((u >> 16) & 1u);
    return (ushort_t)(r >> 16);
}

// async global -> LDS, 16 bytes/lane; lds dest is wave-uniform base (+lane*16 by HW)
__device__ __forceinline__ void gload16(const void* g, void* l) {
    __builtin_amdgcn_global_load_lds(
        (const __attribute__((address_space(1))) void*)g,
        (__attribute__((address_space(3))) void*)l, 16, 0, 0);
}

// word = bf16(k) | bf16(th)<<16 -> c = 1-sigmoid(k), v = sigmoid(k)*g(th)
__device__ __forceinline__ void gates(uint_t w, float& c, float& v) {
    float k  = __uint_as_float((w & 0xffffu) << 16);
    float th = __uint_as_float(w & 0xffff0000u);
    float ek = __expf(k);
    c = 1.0f / (1.0f + ek);        // 1 - sigmoid(k)
    float z = 1.0f - c;            // sigmoid(k)
    float g = (th >= 0.0f) ? (th + 0.5f) : (1.0f / (1.0f + __expf(-th)));
    v = z * g;
}

// ---------------- convert x, Wz, Wh to bf16 (single pass) ----------------
__global__ __launch_bounds__(256)
void convert_all(const float* __restrict__ x, const float* __restrict__ Wz,
                 const float* __restrict__ Wh, ushort_t* __restrict__ dst) {
    size_t i8 = ((size_t)blockIdx.x * 256 + threadIdx.x) * 8;
    const size_t XN = (size_t)Mq * Dq;
    const size_t WN = (size_t)Hq * Dq;
    const float* src; size_t off;
    if (i8 < XN)            { src = x;  off = i8; }
    else if (i8 < XN + WN)  { src = Wz; off = i8 - XN; }
    else                    { src = Wh; off = i8 - XN - WN; }
    float4 a = *reinterpret_cast<const float4*>(src + off);
    float4 b = *reinterpret_cast<const float4*>(src + off + 4);
    uint4 o;
    o.x = (uint_t)f2bf(a.x) | ((uint_t)f2bf(a.y) << 16);
    o.y = (uint_t)f2bf(a.z) | ((uint_t)f2bf(a.w) << 16);
    o.z = (uint_t)f2bf(b.x) | ((uint_t)f2bf(b.y) << 16);
    o.w = (uint_t)f2bf(b.z) | ((uint_t)f2bf(b.w) << 16);
    *reinterpret_cast<uint4*>(dst + i8) = o;
}

// ---------------- fused dual GEMM (clean epilogue) ----------------
__global__ __launch_bounds__(256, 2)
void gemm_fused(const ushort_t* __restrict__ xb, const ushort_t* __restrict__ wb,
                const float* __restrict__ bz, const float* __restrict__ bh,
                uint_t* __restrict__ kvout) {
    __shared__ __align__(16) ushort_t As [128 * 64];
    __shared__ __align__(16) ushort_t Bzs[128 * 64];
    __shared__ __align__(16) ushort_t Bhs[128 * 64];

    const int tid  = threadIdx.x;
    const int lane = tid & 63;
    const int wave = tid >> 6;
    const int wm = (wave >> 1) * 64;
    const int wn = (wave & 1) * 64;
    const int mBase = blockIdx.x * 128;
    const int nBase = blockIdx.y * 128;
    const ushort_t* Wzb = wb;
    const ushort_t* Whb = wb + (size_t)Hq * Dq;

    f32x4 zero = {0.f, 0.f, 0.f, 0.f};
    f32x4 accz[4][4], acch[4][4];
#pragma unroll
    for (int i = 0; i < 4; ++i)
#pragma unroll
        for (int j = 0; j < 4; ++j) { accz[i][j] = zero; acch[i][j] = zero; }

    const int rowInW = lane >> 3;
    const int ccG = (lane & 7) ^ rowInW;   // xor-swizzled global chunk
    const int swz = lane & 7;              // read-side swizzle

    for (int k0 = 0; k0 < Dq; k0 += 64) {
#pragma unroll
        for (int j = 0; j < 4; ++j) {
            const int rseg = j * 4 + wave;
            const int row  = rseg * 8 + rowInW;
            const size_t gcol = (size_t)(k0 + ccG * 8);
            gload16(xb  + (size_t)(mBase + row) * Dq + gcol, &As [rseg * 512]);
            gload16(Wzb + (size_t)(nBase + row) * Dq + gcol, &Bzs[rseg * 512]);
            gload16(Whb + (size_t)(nBase + row) * Dq + gcol, &Bhs[rseg * 512]);
        }
        __syncthreads();

#pragma unroll
        for (int ks = 0; ks < 2; ++ks) {
            const int cc = ks * 4 + (lane >> 4);
            const int sc = cc ^ swz;
            bf16x8 af[4], bzf[4], bhf[4];
#pragma unroll
            for (int i = 0; i < 4; ++i) {
                int rowA = wm + i * 16 + (lane & 15);
                af[i] = *reinterpret_cast<const bf16x8*>(&As[rowA * 64 + sc * 8]);
            }
#pragma unroll
            for (int i = 0; i < 4; ++i) {
                int rowB = wn + i * 16 + (lane & 15);
                bzf[i] = *reinterpret_cast<const bf16x8*>(&Bzs[rowB * 64 + sc * 8]);
                bhf[i] = *reinterpret_cast<const bf16x8*>(&Bhs[rowB * 64 + sc * 8]);
            }
#pragma unroll
            for (int mi = 0; mi < 4; ++mi)
#pragma unroll
                for (int ni = 0; ni < 4; ++ni) {
                    accz[mi][ni] = __builtin_amdgcn_mfma_f32_16x16x32_bf16(
                        af[mi], bzf[ni], accz[mi][ni], 0, 0, 0);
                    acch[mi][ni] = __builtin_amdgcn_mfma_f32_16x16x32_bf16(
                        af[mi], bhf[ni], acch[mi][ni], 0, 0, 0);
                }
        }
        __syncthreads();
    }

    const int colL = lane & 15;
    const int rowQ = (lane >> 4) * 4;
#pragma unroll
    for (int mi = 0; mi < 4; ++mi) {
#pragma unroll
        for (int ni = 0; ni < 4; ++ni) {
            int h = nBase + wn + ni * 16 + colL;
            float bzv = bz[h];
            float bhv = bh[h];
#pragma unroll
            for (int r = 0; r < 4; ++r) {
                int bt = mBase + wm + mi * 16 + rowQ + r;
                float kf  = accz[mi][ni][r] + bzv;
                float thf = acch[mi][ni][r] + bhv;
                kvout[(size_t)bt * Hq + h] =
                    (uint_t)f2bf(kf) | ((uint_t)f2bf(thf) << 16);
            }
        }
    }
}

// ---------------- scan phases (shared by coop + fallback kernels) ----------------
// low VGPR (~40): no chunk-resident register caching, so cooperative
// co-residency has 2x capacity margin (512 blocks needed, >=1024 capacity)
__device__ __forceinline__ void phaseA(const uint_t* kv, float2* chAW, int blk, int h) {
    const int b = blk >> 6, c = blk & 63;
    size_t base = ((size_t)b * Tq + (size_t)c * CL) * Hq + h;
    float A = 1.f, W = 0.f;
    for (int t0 = 0; t0 < CL; t0 += 16) {
        uint_t w[16];
#pragma unroll
        for (int j = 0; j < 16; ++j) w[j] = kv[base + (size_t)(t0 + j) * Hq];
#pragma unroll
        for (int j = 0; j < 16; ++j) {
            float cc, vv;
            gates(w[j], cc, vv);
            W = fmaf(cc, W, vv);
            A *= cc;
        }
    }
    chAW[(size_t)blk * Hq + h] = make_float2(A, W);
}

__device__ __forceinline__ void phaseB(const float* h0, const float2* chAW,
                                       float* hstart, int b, int h) {
    float x0 = h0[b * Hq + h];
    float r = (x0 >= 0.f) ? (x0 + 0.5f) : (1.f / (1.f + __expf(-x0)));
    const float2* p = chAW + (size_t)b * NC * Hq + h;
    float* q = hstart + (size_t)b * NC * Hq + h;
    for (int c0 = 0; c0 < NC; c0 += 16) {
        float2 aw[16];
#pragma unroll
        for (int j = 0; j < 16; ++j) aw[j] = p[(size_t)(c0 + j) * Hq];
#pragma unroll
        for (int j = 0; j < 16; ++j) {
            q[(size_t)(c0 + j) * Hq] = r;
            r = fmaf(aw[j].x, r, aw[j].y);
        }
    }
}

// kv aliases out: 8-deep batch prefetch keeps loads ahead of may-aliasing stores;
// each address is read before written, and only by the same thread.
__device__ __forceinline__ void phaseC(const uint_t* kv, const float* hstart,
                                       float* out, int blk, int h) {
    const int b = blk >> 6, c = blk & 63;
    float r = hstart[(size_t)blk * Hq + h];
    size_t base = ((size_t)b * Tq + (size_t)c * CL) * Hq + h;
    uint_t w[8];
#pragma unroll
    for (int j = 0; j < 8; ++j) w[j] = kv[base + (size_t)j * Hq];
    for (int bt = 0; bt < 8; ++bt) {
        uint_t wn[8];
        if (bt < 7) {
#pragma unroll
            for (int j = 0; j < 8; ++j)
                wn[j] = kv[base + (size_t)((bt + 1) * 8 + j) * Hq];
        }
#pragma unroll
        for (int j = 0; j < 8; ++j) {
            float cc, vv;
            gates(w[j], cc, vv);
            r = fmaf(cc, r, vv);
            out[base + (size_t)(bt * 8 + j) * Hq] = r;
        }
#pragma unroll
        for (int j = 0; j < 8; ++j) w[j] = wn[j];
    }
}

__global__ __launch_bounds__(512, 4)
void scan_coop(const float* __restrict__ h0, float2* chAW, float* hstart, float* out) {
    const int blk = blockIdx.x;        // b*NC + c
    const int h = threadIdx.x;
    const uint_t* kv = reinterpret_cast<const uint_t*>(out);
    phaseA(kv, chAW, blk, h);
    __threadfence();
    cooperative_groups::this_grid().sync();
    if ((blk & 63) == 0) phaseB(h0, chAW, hstart, blk >> 6, h);
    __threadfence();
    cooperative_groups::this_grid().sync();
    phaseC(kv, hstart, out, blk, h);
}

// fallback (non-cooperative) versions of the three phases
__global__ __launch_bounds__(512)
void k_phaseA(const uint_t* __restrict__ kv, float2* __restrict__ chAW) {
    phaseA(kv, chAW, blockIdx.x, threadIdx.x);
}
__global__ __launch_bounds__(512)
void k_phaseB(const float* __restrict__ h0, const float2* __restrict__ chAW,
              float* __restrict__ hstart) {
    int idx = blockIdx.x * 512 + threadIdx.x;   // b*H + h
    phaseB(h0, chAW, hstart, idx >> 9, idx & (Hq - 1));
}
__global__ __launch_bounds__(512)
void k_phaseC(const uint_t* kv, const float* __restrict__ hstart, float* out) {
    phaseC(kv, hstart, out, blockIdx.x, threadIdx.x);
}

extern "C" void kernel_launch(void* const* d_in, const int* in_sizes, int n_in,
                              void* d_out, int out_size, void* d_ws, size_t ws_size,
                              hipStream_t stream) {
    const float* x  = (const float*)d_in[0];
    const float* h0 = (const float*)d_in[1];
    const float* Wz = (const float*)d_in[2];
    const float* bz = (const float*)d_in[3];
    const float* Wh = (const float*)d_in[4];
    const float* bh = (const float*)d_in[5];
    float* out = (float*)d_out;

    // ws layout (~36 MB): xb 32MB | wb 1MB | chAW 2MB | hstart 1MB
    char* ws = (char*)d_ws;
    ushort_t* xb = (ushort_t*)ws;
    ushort_t* wb = xb + (size_t)Mq * Dq;
    float2* chAW = (float2*)(wb + 2 * (size_t)Hq * Dq);
    float* hstart = (float*)((char*)chAW + (size_t)Bq * NC * Hq * sizeof(float2));
    uint_t* kv = (uint_t*)d_out;

    const int totalConv = (Mq * Dq + 2 * Hq * Dq) / (256 * 8);
    convert_all<<<dim3(totalConv), dim3(256), 0, stream>>>(x, Wz, Wh, xb);
    gemm_fused<<<dim3(Mq / 128, Hq / 128), dim3(256), 0, stream>>>(xb, wb, bz, bh, kv);

    const float* h0a = h0; float2* chAWa = chAW; float* hstarta = hstart; float* outa = out;
    void* args[] = {(void*)&h0a, (void*)&chAWa, (void*)&hstarta, (void*)&outa};
    hipError_t e = hipLaunchCooperativeKernel(reinterpret_cast<void*>(scan_coop),
                                              dim3(Bq * NC), dim3(512), args, 0, stream);
    if (e != hipSuccess) {
        // non-cooperative fallback: identical math, 3 dispatches
        k_phaseA<<<dim3(Bq * NC), dim3(512), 0, stream>>>(kv, chAW);
        k_phaseB<<<dim3((Bq * Hq) / 512), dim3(512), 0, stream>>>(h0, chAW, hstart);
        k_phaseC<<<dim3(Bq * NC), dim3(512), 0, stream>>>(kv, hstart, out);
    }
}

// Round 6
// 479.235 us; speedup vs baseline: 1.0384x; 1.0384x over previous
//
#include <hip/hip_runtime.h>
#include <math.h>

#define Bq 8
#define Tq 4096
#define Dq 512
#define Hq 512
#define H2 (Hq / 2)    // 256 h-pairs
#define Mq (Bq * Tq)   // 32768
#define NC 64          // chunks along T
#define CL 64          // chunk length

typedef unsigned short ushort_t;
typedef unsigned int uint_t;
typedef __bf16 bf16x8 __attribute__((ext_vector_type(8)));
typedef float f32x4 __attribute__((ext_vector_type(4)));

__device__ __forceinline__ ushort_t f2bf(float f) {
    unsigned int u = __float_as_uint(f);
    unsigned int r = u + 0x7fffu + ((u >> 16) & 1u);
    return (ushort_t)(r >> 16);
}

// async global -> LDS, 16 bytes/lane; lds dest is wave-uniform base (+lane*16 by HW)
__device__ __forceinline__ void gload16(const void* g, void* l) {
    __builtin_amdgcn_global_load_lds(
        (const __attribute__((address_space(1))) void*)g,
        (__attribute__((address_space(3))) void*)l, 16, 0, 0);
}

// word = bf16(k) | bf16(th)<<16 -> c = 1-sigmoid(k), v = sigmoid(k)*g(th)
__device__ __forceinline__ void gates(uint_t w, float& c, float& v) {
    float k  = __uint_as_float((w & 0xffffu) << 16);
    float th = __uint_as_float(w & 0xffff0000u);
    float ek = __expf(k);
    c = 1.0f / (1.0f + ek);        // 1 - sigmoid(k)
    float z = 1.0f - c;            // sigmoid(k)
    float g = (th >= 0.0f) ? (th + 0.5f) : (1.0f / (1.0f + __expf(-th)));
    v = z * g;
}

// ---------------- convert x, Wz, Wh to bf16 + zero sync words ----------------
__global__ __launch_bounds__(256)
void convert_all(const float* __restrict__ x, const float* __restrict__ Wz,
                 const float* __restrict__ Wh, ushort_t* __restrict__ dst,
                 uint_t* __restrict__ sync) {
    if (blockIdx.x == 0 && threadIdx.x < 16) sync[threadIdx.x] = 0;  // cnt[8] | flag[8]
    size_t i8 = ((size_t)blockIdx.x * 256 + threadIdx.x) * 8;
    const size_t XN = (size_t)Mq * Dq;
    const size_t WN = (size_t)Hq * Dq;
    const float* src; size_t off;
    if (i8 < XN)            { src = x;  off = i8; }
    else if (i8 < XN + WN)  { src = Wz; off = i8 - XN; }
    else                    { src = Wh; off = i8 - XN - WN; }
    float4 a = *reinterpret_cast<const float4*>(src + off);
    float4 b = *reinterpret_cast<const float4*>(src + off + 4);
    uint4 o;
    o.x = (uint_t)f2bf(a.x) | ((uint_t)f2bf(a.y) << 16);
    o.y = (uint_t)f2bf(a.z) | ((uint_t)f2bf(a.w) << 16);
    o.z = (uint_t)f2bf(b.x) | ((uint_t)f2bf(b.y) << 16);
    o.w = (uint_t)f2bf(b.z) | ((uint_t)f2bf(b.w) << 16);
    *reinterpret_cast<uint4*>(dst + i8) = o;
}

// ---------------- fused dual GEMM (clean epilogue, R2 form: 45 us measured) ----------------
__global__ __launch_bounds__(256, 2)
void gemm_fused(const ushort_t* __restrict__ xb, const ushort_t* __restrict__ wb,
                const float* __restrict__ bz, const float* __restrict__ bh,
                uint_t* __restrict__ kvout) {
    __shared__ __align__(16) ushort_t As [128 * 64];
    __shared__ __align__(16) ushort_t Bzs[128 * 64];
    __shared__ __align__(16) ushort_t Bhs[128 * 64];

    const int tid  = threadIdx.x;
    const int lane = tid & 63;
    const int wave = tid >> 6;
    const int wm = (wave >> 1) * 64;
    const int wn = (wave & 1) * 64;
    const int mBase = blockIdx.x * 128;
    const int nBase = blockIdx.y * 128;
    const ushort_t* Wzb = wb;
    const ushort_t* Whb = wb + (size_t)Hq * Dq;

    f32x4 zero = {0.f, 0.f, 0.f, 0.f};
    f32x4 accz[4][4], acch[4][4];
#pragma unroll
    for (int i = 0; i < 4; ++i)
#pragma unroll
        for (int j = 0; j < 4; ++j) { accz[i][j] = zero; acch[i][j] = zero; }

    const int rowInW = lane >> 3;
    const int ccG = (lane & 7) ^ rowInW;   // xor-swizzled global chunk
    const int swz = lane & 7;              // read-side swizzle

    for (int k0 = 0; k0 < Dq; k0 += 64) {
#pragma unroll
        for (int j = 0; j < 4; ++j) {
            const int rseg = j * 4 + wave;
            const int row  = rseg * 8 + rowInW;
            const size_t gcol = (size_t)(k0 + ccG * 8);
            gload16(xb  + (size_t)(mBase + row) * Dq + gcol, &As [rseg * 512]);
            gload16(Wzb + (size_t)(nBase + row) * Dq + gcol, &Bzs[rseg * 512]);
            gload16(Whb + (size_t)(nBase + row) * Dq + gcol, &Bhs[rseg * 512]);
        }
        __syncthreads();

#pragma unroll
        for (int ks = 0; ks < 2; ++ks) {
            const int cc = ks * 4 + (lane >> 4);
            const int sc = cc ^ swz;
            bf16x8 af[4], bzf[4], bhf[4];
#pragma unroll
            for (int i = 0; i < 4; ++i) {
                int rowA = wm + i * 16 + (lane & 15);
                af[i] = *reinterpret_cast<const bf16x8*>(&As[rowA * 64 + sc * 8]);
            }
#pragma unroll
            for (int i = 0; i < 4; ++i) {
                int rowB = wn + i * 16 + (lane & 15);
                bzf[i] = *reinterpret_cast<const bf16x8*>(&Bzs[rowB * 64 + sc * 8]);
                bhf[i] = *reinterpret_cast<const bf16x8*>(&Bhs[rowB * 64 + sc * 8]);
            }
#pragma unroll
            for (int mi = 0; mi < 4; ++mi)
#pragma unroll
                for (int ni = 0; ni < 4; ++ni) {
                    accz[mi][ni] = __builtin_amdgcn_mfma_f32_16x16x32_bf16(
                        af[mi], bzf[ni], accz[mi][ni], 0, 0, 0);
                    acch[mi][ni] = __builtin_amdgcn_mfma_f32_16x16x32_bf16(
                        af[mi], bhf[ni], acch[mi][ni], 0, 0, 0);
                }
        }
        __syncthreads();
    }

    const int colL = lane & 15;
    const int rowQ = (lane >> 4) * 4;
#pragma unroll
    for (int mi = 0; mi < 4; ++mi) {
#pragma unroll
        for (int ni = 0; ni < 4; ++ni) {
            int h = nBase + wn + ni * 16 + colL;
            float bzv = bz[h];
            float bhv = bh[h];
#pragma unroll
            for (int r = 0; r < 4; ++r) {
                int bt = mBase + wm + mi * 16 + rowQ + r;
                float kf  = accz[mi][ni][r] + bzv;
                float thf = acch[mi][ni][r] + bhv;
                kvout[(size_t)bt * Hq + h] =
                    (uint_t)f2bf(kf) | ((uint_t)f2bf(thf) << 16);
            }
        }
    }
}

// ---------------- single-dispatch 3-phase scan with per-batch flag sync ----------------
// Dependency is per-b only. Every block publishes its chunk partial BEFORE any
// wait, so progress never requires an unscheduled block (grid 512 <= capacity
// ~1024 at <=128 VGPR, 2x margin). kv aliases out: each block touches only its
// own chunk's addresses; reads precede writes within each thread.
__global__ __launch_bounds__(256, 4)
void scan_onepass(const float* __restrict__ h0, float4* chAW, float2* hstart,
                  uint_t* cnt, uint_t* flag, float* out) {
    const int blk = blockIdx.x;        // b*NC + c
    const int b = blk >> 6;
    const int c = blk & 63;
    const int h2 = threadIdx.x;        // h-pair index
    const uint2* kv2 = reinterpret_cast<const uint2*>(out);
    float2* out2 = reinterpret_cast<float2*>(out);
    const size_t base = ((size_t)b * Tq + (size_t)c * CL) * H2 + h2;

    // --- phase A: per-chunk affine partial from packed kv ---
    float A0 = 1.f, W0 = 0.f, A1 = 1.f, W1 = 0.f;
    for (int t0 = 0; t0 < CL; t0 += 16) {
        uint2 w[16];
#pragma unroll
        for (int j = 0; j < 16; ++j) w[j] = kv2[base + (size_t)(t0 + j) * H2];
#pragma unroll
        for (int j = 0; j < 16; ++j) {
            float c0, v0, c1, v1;
            gates(w[j].x, c0, v0);
            gates(w[j].y, c1, v1);
            W0 = fmaf(c0, W0, v0); A0 *= c0;
            W1 = fmaf(c1, W1, v1); A1 *= c1;
        }
    }
    chAW[(size_t)blk * H2 + h2] = make_float4(A0, W0, A1, W1);
    __threadfence();
    __syncthreads();
    if (threadIdx.x == 0)
        __hip_atomic_fetch_add(&cnt[b], 1u, __ATOMIC_RELEASE, __HIP_MEMORY_SCOPE_AGENT);

    // --- phase B: chunk-0 block combines once all partials of batch b are in ---
    if (c == 0) {
        while (__hip_atomic_load(&cnt[b], __ATOMIC_ACQUIRE, __HIP_MEMORY_SCOPE_AGENT) < NC)
            __builtin_amdgcn_s_sleep(16);
        float2 x0 = reinterpret_cast<const float2*>(h0)[b * H2 + h2];
        float r0 = (x0.x >= 0.f) ? (x0.x + 0.5f) : (1.f / (1.f + __expf(-x0.x)));
        float r1 = (x0.y >= 0.f) ? (x0.y + 0.5f) : (1.f / (1.f + __expf(-x0.y)));
        const float4* p = chAW + (size_t)b * NC * H2 + h2;
        float2* q = hstart + (size_t)b * NC * H2 + h2;
        for (int c0 = 0; c0 < NC; c0 += 8) {
            float4 aw[8];
#pragma unroll
            for (int j = 0; j < 8; ++j) aw[j] = p[(size_t)(c0 + j) * H2];
#pragma unroll
            for (int j = 0; j < 8; ++j) {
                q[(size_t)(c0 + j) * H2] = make_float2(r0, r1);
                r0 = fmaf(aw[j].x, r0, aw[j].y);
                r1 = fmaf(aw[j].z, r1, aw[j].w);
            }
        }
        __threadfence();
        __syncthreads();
        if (threadIdx.x == 0)
            __hip_atomic_store(&flag[b], 1u, __ATOMIC_RELEASE, __HIP_MEMORY_SCOPE_AGENT);
    }

    // --- wait for hstart of batch b (every thread does >=1 acquire load) ---
    while (__hip_atomic_load(&flag[b], __ATOMIC_ACQUIRE, __HIP_MEMORY_SCOPE_AGENT) == 0)
        __builtin_amdgcn_s_sleep(16);

    // --- phase C: replay with true prefix (8-deep alias-safe prefetch) ---
    float2 hs = hstart[(size_t)blk * H2 + h2];
    float r0 = hs.x, r1 = hs.y;
    uint2 w[8];
#pragma unroll
    for (int j = 0; j < 8; ++j) w[j] = kv2[base + (size_t)j * H2];
    for (int bt = 0; bt < 8; ++bt) {
        uint2 wn[8];
        if (bt < 7) {
#pragma unroll
            for (int j = 0; j < 8; ++j)
                wn[j] = kv2[base + (size_t)((bt + 1) * 8 + j) * H2];
        }
#pragma unroll
        for (int j = 0; j < 8; ++j) {
            float c0, v0, c1, v1;
            gates(w[j].x, c0, v0);
            gates(w[j].y, c1, v1);
            r0 = fmaf(c0, r0, v0);
            r1 = fmaf(c1, r1, v1);
            out2[base + (size_t)(bt * 8 + j) * H2] = make_float2(r0, r1);
        }
#pragma unroll
        for (int j = 0; j < 8; ++j) w[j] = wn[j];
    }
}

extern "C" void kernel_launch(void* const* d_in, const int* in_sizes, int n_in,
                              void* d_out, int out_size, void* d_ws, size_t ws_size,
                              hipStream_t stream) {
    const float* x  = (const float*)d_in[0];
    const float* h0 = (const float*)d_in[1];
    const float* Wz = (const float*)d_in[2];
    const float* bz = (const float*)d_in[3];
    const float* Wh = (const float*)d_in[4];
    const float* bh = (const float*)d_in[5];
    float* out = (float*)d_out;

    // ws layout (~36 MB): xb 32MB | wb 1MB | chAW 2MB | hstart 1MB | sync 64B
    char* ws = (char*)d_ws;
    ushort_t* xb = (ushort_t*)ws;
    ushort_t* wb = xb + (size_t)Mq * Dq;
    float4* chAW = (float4*)(wb + 2 * (size_t)Hq * Dq);
    float2* hstart = (float2*)((char*)chAW + (size_t)Bq * NC * H2 * sizeof(float4));
    uint_t* sync = (uint_t*)((char*)hstart + (size_t)Bq * NC * H2 * sizeof(float2));
    uint_t* cnt = sync;          // [8]
    uint_t* flag = sync + 8;     // [8]
    uint_t* kv = (uint_t*)d_out;

    const int totalConv = (Mq * Dq + 2 * Hq * Dq) / (256 * 8);
    convert_all<<<dim3(totalConv), dim3(256), 0, stream>>>(x, Wz, Wh, xb, sync);
    gemm_fused<<<dim3(Mq / 128, Hq / 128), dim3(256), 0, stream>>>(xb, wb, bz, bh, kv);
    scan_onepass<<<dim3(Bq * NC), dim3(256), 0, stream>>>(h0, chAW, hstart, cnt, flag, out);
}

// Round 7
// 226.089 us; speedup vs baseline: 2.2011x; 2.1197x over previous
//
#include <hip/hip_runtime.h>
#include <math.h>

#define Bq 8
#define Tq 4096
#define Dq 512
#define Hq 512
#define H2 (Hq / 2)    // 256 h-pairs
#define Mq (Bq * Tq)   // 32768
#define NC 64          // chunks along T
#define CL 64          // chunk length

typedef unsigned short ushort_t;
typedef unsigned int uint_t;
typedef unsigned long long u64_t;
typedef __bf16 bf16x8 __attribute__((ext_vector_type(8)));
typedef float f32x4 __attribute__((ext_vector_type(4)));

union F2U { float2 f; u64_t u; };

__device__ __forceinline__ ushort_t f2bf(float f) {
    unsigned int u = __float_as_uint(f);
    unsigned int r = u + 0x7fffu + ((u >> 16) & 1u);
    return (ushort_t)(r >> 16);
}

__device__ __forceinline__ void gload16(const void* g, void* l) {
    __builtin_amdgcn_global_load_lds(
        (const __attribute__((address_space(1))) void*)g,
        (__attribute__((address_space(3))) void*)l, 16, 0, 0);
}

// word = bf16(k) | bf16(th)<<16 -> c = 1-sigmoid(k), v = sigmoid(k)*g(th)
__device__ __forceinline__ void gates(uint_t w, float& c, float& v) {
    float k  = __uint_as_float((w & 0xffffu) << 16);
    float th = __uint_as_float(w & 0xffff0000u);
    float ek = __expf(k);
    c = 1.0f / (1.0f + ek);
    float z = 1.0f - c;
    float g = (th >= 0.0f) ? (th + 0.5f) : (1.0f / (1.0f + __expf(-th)));
    v = z * g;
}

// relaxed agent-scope atomics: plain sc1 (LLC-coherent) ops, NO buffer_inv/wbl2
__device__ __forceinline__ void put64(u64_t* p, u64_t v) {
    __hip_atomic_store(p, v, __ATOMIC_RELAXED, __HIP_MEMORY_SCOPE_AGENT);
}
__device__ __forceinline__ u64_t get64(const u64_t* p) {
    return __hip_atomic_load(p, __ATOMIC_RELAXED, __HIP_MEMORY_SCOPE_AGENT);
}

// ---------------- convert x, Wz, Wh to bf16 + zero sync words ----------------
__global__ __launch_bounds__(256)
void convert_all(const float* __restrict__ x, const float* __restrict__ Wz,
                 const float* __restrict__ Wh, ushort_t* __restrict__ dst,
                 uint_t* __restrict__ sync) {
    if (blockIdx.x == 0) sync[threadIdx.x] = 0;  // cnt[b*16] / flag[128+b*16]
    size_t i8 = ((size_t)blockIdx.x * 256 + threadIdx.x) * 8;
    const size_t XN = (size_t)Mq * Dq;
    const size_t WN = (size_t)Hq * Dq;
    const float* src; size_t off;
    if (i8 < XN)            { src = x;  off = i8; }
    else if (i8 < XN + WN)  { src = Wz; off = i8 - XN; }
    else                    { src = Wh; off = i8 - XN - WN; }
    float4 a = *reinterpret_cast<const float4*>(src + off);
    float4 b = *reinterpret_cast<const float4*>(src + off + 4);
    uint4 o;
    o.x = (uint_t)f2bf(a.x) | ((uint_t)f2bf(a.y) << 16);
    o.y = (uint_t)f2bf(a.z) | ((uint_t)f2bf(a.w) << 16);
    o.z = (uint_t)f2bf(b.x) | ((uint_t)f2bf(b.y) << 16);
    o.w = (uint_t)f2bf(b.z) | ((uint_t)f2bf(b.w) << 16);
    *reinterpret_cast<uint4*>(dst + i8) = o;
}

// ---------------- fused dual GEMM (clean epilogue; 45 us measured in R2) ----------------
__global__ __launch_bounds__(256, 2)
void gemm_fused(const ushort_t* __restrict__ xb, const ushort_t* __restrict__ wb,
                const float* __restrict__ bz, const float* __restrict__ bh,
                uint_t* __restrict__ kvout) {
    __shared__ __align__(16) ushort_t As [128 * 64];
    __shared__ __align__(16) ushort_t Bzs[128 * 64];
    __shared__ __align__(16) ushort_t Bhs[128 * 64];

    const int tid  = threadIdx.x;
    const int lane = tid & 63;
    const int wave = tid >> 6;
    const int wm = (wave >> 1) * 64;
    const int wn = (wave & 1) * 64;
    const int mBase = blockIdx.x * 128;
    const int nBase = blockIdx.y * 128;
    const ushort_t* Wzb = wb;
    const ushort_t* Whb = wb + (size_t)Hq * Dq;

    f32x4 zero = {0.f, 0.f, 0.f, 0.f};
    f32x4 accz[4][4], acch[4][4];
#pragma unroll
    for (int i = 0; i < 4; ++i)
#pragma unroll
        for (int j = 0; j < 4; ++j) { accz[i][j] = zero; acch[i][j] = zero; }

    const int rowInW = lane >> 3;
    const int ccG = (lane & 7) ^ rowInW;
    const int swz = lane & 7;

    for (int k0 = 0; k0 < Dq; k0 += 64) {
#pragma unroll
        for (int j = 0; j < 4; ++j) {
            const int rseg = j * 4 + wave;
            const int row  = rseg * 8 + rowInW;
            const size_t gcol = (size_t)(k0 + ccG * 8);
            gload16(xb  + (size_t)(mBase + row) * Dq + gcol, &As [rseg * 512]);
            gload16(Wzb + (size_t)(nBase + row) * Dq + gcol, &Bzs[rseg * 512]);
            gload16(Whb + (size_t)(nBase + row) * Dq + gcol, &Bhs[rseg * 512]);
        }
        __syncthreads();

#pragma unroll
        for (int ks = 0; ks < 2; ++ks) {
            const int cc = ks * 4 + (lane >> 4);
            const int sc = cc ^ swz;
            bf16x8 af[4], bzf[4], bhf[4];
#pragma unroll
            for (int i = 0; i < 4; ++i) {
                int rowA = wm + i * 16 + (lane & 15);
                af[i] = *reinterpret_cast<const bf16x8*>(&As[rowA * 64 + sc * 8]);
            }
#pragma unroll
            for (int i = 0; i < 4; ++i) {
                int rowB = wn + i * 16 + (lane & 15);
                bzf[i] = *reinterpret_cast<const bf16x8*>(&Bzs[rowB * 64 + sc * 8]);
                bhf[i] = *reinterpret_cast<const bf16x8*>(&Bhs[rowB * 64 + sc * 8]);
            }
#pragma unroll
            for (int mi = 0; mi < 4; ++mi)
#pragma unroll
                for (int ni = 0; ni < 4; ++ni) {
                    accz[mi][ni] = __builtin_amdgcn_mfma_f32_16x16x32_bf16(
                        af[mi], bzf[ni], accz[mi][ni], 0, 0, 0);
                    acch[mi][ni] = __builtin_amdgcn_mfma_f32_16x16x32_bf16(
                        af[mi], bhf[ni], acch[mi][ni], 0, 0, 0);
                }
        }
        __syncthreads();
    }

    const int colL = lane & 15;
    const int rowQ = (lane >> 4) * 4;
#pragma unroll
    for (int mi = 0; mi < 4; ++mi) {
#pragma unroll
        for (int ni = 0; ni < 4; ++ni) {
            int h = nBase + wn + ni * 16 + colL;
            float bzv = bz[h];
            float bhv = bh[h];
#pragma unroll
            for (int r = 0; r < 4; ++r) {
                int bt = mBase + wm + mi * 16 + rowQ + r;
                float kf  = accz[mi][ni][r] + bzv;
                float thf = acch[mi][ni][r] + bhv;
                kvout[(size_t)bt * Hq + h] =
                    (uint_t)f2bf(kf) | ((uint_t)f2bf(thf) << 16);
            }
        }
    }
}

// ---------------- single-dispatch 3-phase scan, fence-free LLC sync ----------------
__global__ __launch_bounds__(256, 4)
void scan_onepass(const float* __restrict__ h0, u64_t* chAW, u64_t* hstart,
                  uint_t* cnt, uint_t* flag, float* out) {
    const int blk = blockIdx.x;        // b*NC + c
    const int b = blk >> 6;
    const int c = blk & 63;
    const int h2 = threadIdx.x;
    const uint2* kv2 = reinterpret_cast<const uint2*>(out);
    float2* out2 = reinterpret_cast<float2*>(out);
    const size_t base = ((size_t)b * Tq + (size_t)c * CL) * H2 + h2;

    // phase A: per-chunk affine partial (normal cached kv reads)
    float A0 = 1.f, W0 = 0.f, A1 = 1.f, W1 = 0.f;
    for (int t0 = 0; t0 < CL; t0 += 16) {
        uint2 w[16];
#pragma unroll
        for (int j = 0; j < 16; ++j) w[j] = kv2[base + (size_t)(t0 + j) * H2];
#pragma unroll
        for (int j = 0; j < 16; ++j) {
            float c0, v0, c1, v1;
            gates(w[j].x, c0, v0);
            gates(w[j].y, c1, v1);
            W0 = fmaf(c0, W0, v0); A0 *= c0;
            W1 = fmaf(c1, W1, v1); A1 *= c1;
        }
    }
    {
        F2U p0; p0.f = make_float2(A0, W0);
        F2U p1; p1.f = make_float2(A1, W1);
        put64(&chAW[(size_t)blk * Hq + 2 * h2 + 0], p0.u);
        put64(&chAW[(size_t)blk * Hq + 2 * h2 + 1], p1.u);
    }
    __syncthreads();   // vmcnt(0) drained per wave before barrier -> stores at LLC
    if (threadIdx.x == 0)
        __hip_atomic_fetch_add(&cnt[b * 16], 1u, __ATOMIC_RELAXED, __HIP_MEMORY_SCOPE_AGENT);

    // phase B: chunk-0 block combines the 64 partials of its batch
    if (c == 0) {
        if (threadIdx.x == 0) {
            while (__hip_atomic_load(&cnt[b * 16], __ATOMIC_RELAXED,
                                     __HIP_MEMORY_SCOPE_AGENT) < NC)
                __builtin_amdgcn_s_sleep(8);
        }
        __syncthreads();
        asm volatile("" ::: "memory");
        float2 x0 = reinterpret_cast<const float2*>(h0)[b * H2 + h2];
        float r0 = (x0.x >= 0.f) ? (x0.x + 0.5f) : (1.f / (1.f + __expf(-x0.x)));
        float r1 = (x0.y >= 0.f) ? (x0.y + 0.5f) : (1.f / (1.f + __expf(-x0.y)));
        const u64_t* p = chAW + (size_t)b * NC * Hq + 2 * h2;
        u64_t* q = hstart + (size_t)b * NC * Hq + 2 * h2;
        for (int c0 = 0; c0 < NC; c0 += 8) {
            F2U aw0[8], aw1[8];
#pragma unroll
            for (int j = 0; j < 8; ++j) {
                aw0[j].u = get64(&p[(size_t)(c0 + j) * Hq]);
                aw1[j].u = get64(&p[(size_t)(c0 + j) * Hq + 1]);
            }
#pragma unroll
            for (int j = 0; j < 8; ++j) {
                F2U e; e.f = make_float2(r0, r1);     // pre-state for chunk c0+j
                put64(&q[(size_t)(c0 + j) * Hq], e.u);
                r0 = fmaf(aw0[j].f.x, r0, aw0[j].f.y);
                r1 = fmaf(aw1[j].f.x, r1, aw1[j].f.y);
            }
        }
        __syncthreads();
        if (threadIdx.x == 0)
            __hip_atomic_store(&flag[b * 16], 1u, __ATOMIC_RELAXED, __HIP_MEMORY_SCOPE_AGENT);
    }

    // wait for hstart of batch b
    if (threadIdx.x == 0) {
        while (__hip_atomic_load(&flag[b * 16], __ATOMIC_RELAXED,
                                 __HIP_MEMORY_SCOPE_AGENT) == 0)
            __builtin_amdgcn_s_sleep(8);
    }
    __syncthreads();
    asm volatile("" ::: "memory");

    // phase C: replay with true prefix (8-deep alias-safe prefetch)
    F2U hs; hs.u = get64(&hstart[(size_t)blk * Hq + 2 * h2]);
    float r0 = hs.f.x, r1 = hs.f.y;
    uint2 w[8];
#pragma unroll
    for (int j = 0; j < 8; ++j) w[j] = kv2[base + (size_t)j * H2];
    for (int bt = 0; bt < 8; ++bt) {
        uint2 wn[8];
        if (bt < 7) {
#pragma unroll
            for (int j = 0; j < 8; ++j)
                wn[j] = kv2[base + (size_t)((bt + 1) * 8 + j) * H2];
        }
#pragma unroll
        for (int j = 0; j < 8; ++j) {
            float c0, v0, c1, v1;
            gates(w[j].x, c0, v0);
            gates(w[j].y, c1, v1);
            r0 = fmaf(c0, r0, v0);
            r1 = fmaf(c1, r1, v1);
            out2[base + (size_t)(bt * 8 + j) * H2] = make_float2(r0, r1);
        }
#pragma unroll
        for (int j = 0; j < 8; ++j) w[j] = wn[j];
    }
}

extern "C" void kernel_launch(void* const* d_in, const int* in_sizes, int n_in,
                              void* d_out, int out_size, void* d_ws, size_t ws_size,
                              hipStream_t stream) {
    const float* x  = (const float*)d_in[0];
    const float* h0 = (const float*)d_in[1];
    const float* Wz = (const float*)d_in[2];
    const float* bz = (const float*)d_in[3];
    const float* Wh = (const float*)d_in[4];
    const float* bh = (const float*)d_in[5];
    float* out = (float*)d_out;

    // ws layout (~37 MB): xb 32MB | wb 1MB | chAW 2MB | hstart 2MB | sync 1KB
    char* ws = (char*)d_ws;
    ushort_t* xb = (ushort_t*)ws;
    ushort_t* wb = xb + (size_t)Mq * Dq;
    u64_t* chAW = (u64_t*)(wb + 2 * (size_t)Hq * Dq);      // [512 blk][512 h]
    u64_t* hstart = chAW + (size_t)Bq * NC * Hq;           // [512 blk][256 pairs] (Hq stride)
    uint_t* sync = (uint_t*)(hstart + (size_t)Bq * NC * Hq);
    uint_t* cnt = sync;            // cnt[b*16]
    uint_t* flag = sync + 128;     // flag[b*16]
    uint_t* kv = (uint_t*)d_out;

    const int totalConv = (Mq * Dq + 2 * Hq * Dq) / (256 * 8);
    convert_all<<<dim3(totalConv), dim3(256), 0, stream>>>(x, Wz, Wh, xb, sync);
    gemm_fused<<<dim3(Mq / 128, Hq / 128), dim3(256), 0, stream>>>(xb, wb, bz, bh, kv);
    scan_onepass<<<dim3(Bq * NC), dim3(256), 0, stream>>>(h0, chAW, hstart, cnt, flag, out);
}